// Round 1
// baseline (389.239 us; speedup 1.0000x reference)
//
#include <hip/hip_runtime.h>
#include <hip/hip_bf16.h>

// Problem constants: B=4, S=1024, D=1024, H=16, DK=DV=64
// Output 0: out [B,S,D] f32 (4 Mi elems). Output 1: attn [B,H,S,S] f32 (64 Mi elems).
// NOTE: softmax is over the QUERY axis (axis=2): attn[b,h,q,k] = exp(s[q,k]) / sum_q' exp(s[q',k]).

typedef __bf16 bf16;
typedef bf16 bf16x4 __attribute__((ext_vector_type(4)));
typedef bf16 bf16x8 __attribute__((ext_vector_type(8)));
typedef float f32x4 __attribute__((ext_vector_type(4)));

#define MFMA(a, b, c) __builtin_amdgcn_mfma_f32_16x16x32_bf16((a), (b), (c), 0, 0, 0)

__device__ __forceinline__ bf16 f2b(float x) { return (bf16)x; }

// ---------------------------------------------------------------------------
// Weight transpose: W f32 [K=1024][N=1024] -> WT bf16 [N][K]
// ---------------------------------------------------------------------------
__global__ __launch_bounds__(256) void k_transpose(
    const float* __restrict__ W0, const float* __restrict__ W1,
    const float* __restrict__ W2, const float* __restrict__ W3,
    bf16* __restrict__ T0, bf16* __restrict__ T1,
    bf16* __restrict__ T2, bf16* __restrict__ T3)
{
    const float* W = blockIdx.z == 0 ? W0 : blockIdx.z == 1 ? W1 : blockIdx.z == 2 ? W2 : W3;
    bf16*        T = blockIdx.z == 0 ? T0 : blockIdx.z == 1 ? T1 : blockIdx.z == 2 ? T2 : T3;
    __shared__ float tile[32][33];
    const int t = threadIdx.x;
    const int r = t >> 3, c = (t & 7) * 4;
    {
        const float4 v = *(const float4*)(W + (size_t)(blockIdx.y * 32 + r) * 1024 + blockIdx.x * 32 + c);
        tile[r][c + 0] = v.x; tile[r][c + 1] = v.y; tile[r][c + 2] = v.z; tile[r][c + 3] = v.w;
    }
    __syncthreads();
    bf16x4 o = { f2b(tile[c + 0][r]), f2b(tile[c + 1][r]), f2b(tile[c + 2][r]), f2b(tile[c + 3][r]) };
    *(bf16x4*)(T + (size_t)(blockIdx.x * 32 + r) * 1024 + blockIdx.y * 32 + c) = o;
}

// ---------------------------------------------------------------------------
// Projection GEMM: X f32 [4096][1024] @ WT^T -> per-head bf16 tensors.
// z=0: q (scaled by 1/8) -> qh [B,H,S,64]; z=1: k -> kh [B,H,S,64];
// z=2: v -> vTh [B,H,64,S] (transposed store for PV B-fragments).
// 128x128 tile, BK=64, 4 waves 2x2 each 64x64.
// ---------------------------------------------------------------------------
__global__ __launch_bounds__(256) void k_proj(
    const float* __restrict__ Xq, const float* __restrict__ Xk, const float* __restrict__ Xv,
    const bf16* __restrict__ WTq, const bf16* __restrict__ WTk, const bf16* __restrict__ WTv,
    bf16* __restrict__ qh, bf16* __restrict__ kh, bf16* __restrict__ vTh)
{
    const int z = blockIdx.z;
    const float* X = z == 0 ? Xq : z == 1 ? Xk : Xv;
    const bf16* WT = z == 0 ? WTq : z == 1 ? WTk : WTv;

    __shared__ bf16 As[128 * 72];   // +8 pad: 2-way (free) bank pattern on frag reads
    __shared__ bf16 Bs[128 * 72];

    const int tid = threadIdx.x;
    const int lane = tid & 63, w = tid >> 6;
    const int lr = lane & 15, lg = lane >> 4;
    const int wm = w >> 1, wn = w & 1;
    const int m0 = blockIdx.y * 128, n0 = blockIdx.x * 128;

    f32x4 acc[4][4] = {};

    for (int k0 = 0; k0 < 1024; k0 += 64) {
        #pragma unroll
        for (int i = 0; i < 4; ++i) {
            const int lin = i * 2048 + tid * 8;
            const int rr = lin >> 6, cc = lin & 63;
            const float4 v0 = *(const float4*)(X + (size_t)(m0 + rr) * 1024 + k0 + cc);
            const float4 v1 = *(const float4*)(X + (size_t)(m0 + rr) * 1024 + k0 + cc + 4);
            bf16x8 o = { f2b(v0.x), f2b(v0.y), f2b(v0.z), f2b(v0.w),
                         f2b(v1.x), f2b(v1.y), f2b(v1.z), f2b(v1.w) };
            *(bf16x8*)&As[rr * 72 + cc] = o;
            *(bf16x8*)&Bs[rr * 72 + cc] = *(const bf16x8*)(WT + (size_t)(n0 + rr) * 1024 + k0 + cc);
        }
        __syncthreads();
        #pragma unroll
        for (int ks = 0; ks < 2; ++ks) {
            bf16x8 a[4], bb[4];
            #pragma unroll
            for (int fm = 0; fm < 4; ++fm)
                a[fm] = *(const bf16x8*)&As[(wm * 64 + fm * 16 + lr) * 72 + ks * 32 + lg * 8];
            #pragma unroll
            for (int fn = 0; fn < 4; ++fn)
                bb[fn] = *(const bf16x8*)&Bs[(wn * 64 + fn * 16 + lr) * 72 + ks * 32 + lg * 8];
            #pragma unroll
            for (int fm = 0; fm < 4; ++fm)
                #pragma unroll
                for (int fn = 0; fn < 4; ++fn)
                    acc[fm][fn] = MFMA(a[fm], bb[fn], acc[fm][fn]);
        }
        __syncthreads();
    }

    if (z < 2) {
        const float scale = (z == 0) ? 0.125f : 1.0f;  // fold 1/sqrt(DK) into q
        bf16* dst = (z == 0) ? qh : kh;
        #pragma unroll
        for (int fm = 0; fm < 4; ++fm)
            #pragma unroll
            for (int fn = 0; fn < 4; ++fn)
                #pragma unroll
                for (int r = 0; r < 4; ++r) {
                    const int m = m0 + wm * 64 + fm * 16 + lg * 4 + r;
                    const int n = n0 + wn * 64 + fn * 16 + lr;
                    const int b = m >> 10, s = m & 1023, h = n >> 6, d = n & 63;
                    dst[(((size_t)(b * 16 + h)) * 1024 + s) * 64 + d] = f2b(acc[fm][fn][r] * scale);
                }
    } else {
        #pragma unroll
        for (int fm = 0; fm < 4; ++fm)
            #pragma unroll
            for (int fn = 0; fn < 4; ++fn) {
                const int m = m0 + wm * 64 + fm * 16 + lg * 4;   // 4 consecutive s
                const int n = n0 + wn * 64 + fn * 16 + lr;
                const int b = m >> 10, s = m & 1023, h = n >> 6, d = n & 63;
                bf16x4 o = { f2b(acc[fm][fn][0]), f2b(acc[fm][fn][1]),
                             f2b(acc[fm][fn][2]), f2b(acc[fm][fn][3]) };
                *(bf16x4*)&vTh[(((size_t)(b * 16 + h)) * 64 + d) * 1024 + s] = o;
            }
    }
}

// ---------------------------------------------------------------------------
// Column softmax denominators: inv_colsum[bh][kk] = 1 / sum_q exp(s[q][kk]).
// Grid: x = kk-tile (8 x 128 cols), y = bh (64). Scores recomputed via MFMA.
// ---------------------------------------------------------------------------
__global__ __launch_bounds__(256) void k_colsum(
    const bf16* __restrict__ qh, const bf16* __restrict__ kh,
    const unsigned char* __restrict__ mask, float* __restrict__ inv_colsum)
{
    const int bh = blockIdx.y;
    const int b = bh >> 4;
    const int kk0 = blockIdx.x * 128;
    const bf16* qb = qh + (size_t)bh * 1024 * 64;
    const bf16* kb = kh + (size_t)bh * 1024 * 64;

    const int tid = threadIdx.x;
    const int lane = tid & 63, w = tid >> 6;
    const int lr = lane & 15, lg = lane >> 4;
    const int wm = w >> 1, wn = w & 1;

    bf16x8 bfr[4][2];
    #pragma unroll
    for (int fn = 0; fn < 4; ++fn)
        #pragma unroll
        for (int ks = 0; ks < 2; ++ks)
            bfr[fn][ks] = *(const bf16x8*)(kb + (size_t)(kk0 + wn * 64 + fn * 16 + lr) * 64 + ks * 32 + lg * 8);

    float colacc[4] = {0.f, 0.f, 0.f, 0.f};

    for (int q0 = 0; q0 < 1024; q0 += 128) {
        #pragma unroll
        for (int fm = 0; fm < 4; ++fm) {
            const int mrow = q0 + wm * 64 + fm * 16;
            const bf16x8 a0 = *(const bf16x8*)(qb + (size_t)(mrow + lr) * 64 + lg * 8);
            const bf16x8 a1 = *(const bf16x8*)(qb + (size_t)(mrow + lr) * 64 + 32 + lg * 8);
            #pragma unroll
            for (int fn = 0; fn < 4; ++fn) {
                f32x4 c = {0.f, 0.f, 0.f, 0.f};
                c = MFMA(a0, bfr[fn][0], c);
                c = MFMA(a1, bfr[fn][1], c);
                const int col = kk0 + wn * 64 + fn * 16 + lr;
                const int row0 = mrow + lg * 4;
                const size_t mbase = (size_t)b * 1048576 + (size_t)row0 * 1024 + col;
                #pragma unroll
                for (int r = 0; r < 4; ++r)
                    colacc[fn] += mask[mbase + (size_t)r * 1024] ? 0.f : __expf(c[r]);
            }
        }
    }

    __shared__ float csum[2][128];
    #pragma unroll
    for (int fn = 0; fn < 4; ++fn) {
        float v = colacc[fn];
        v += __shfl_xor(v, 16);
        v += __shfl_xor(v, 32);
        if (lane < 16) csum[wm][wn * 64 + fn * 16 + lane] = v;
    }
    __syncthreads();
    if (tid < 128) {
        const float s = csum[0][tid] + csum[1][tid];
        inv_colsum[(size_t)bh * 1024 + kk0 + tid] = 1.0f / s;
    }
}

// ---------------------------------------------------------------------------
// Fused: recompute scores, attn = exp(s)*inv_colsum (write f32 to d_out),
// repack P to LDS (bf16, padded), PV via MFMA -> attn_head [B,S,H*64] bf16.
// Grid: x = q-tile (8 x 128 rows), y = bh (64).
// ---------------------------------------------------------------------------
__global__ __launch_bounds__(256) void k_attn(
    const bf16* __restrict__ qh, const bf16* __restrict__ kh, const bf16* __restrict__ vTh,
    const unsigned char* __restrict__ mask, const float* __restrict__ inv_colsum,
    float* __restrict__ attn_out, bf16* __restrict__ attn_head)
{
    const int bh = blockIdx.y;
    const int b = bh >> 4, h = bh & 15;
    const int q0 = blockIdx.x * 128;
    const bf16* qb = qh + (size_t)bh * 1024 * 64;
    const bf16* kb = kh + (size_t)bh * 1024 * 64;
    const bf16* vb = vTh + (size_t)bh * 64 * 1024;

    const int tid = threadIdx.x;
    const int lane = tid & 63, w = tid >> 6;
    const int lr = lane & 15, lg = lane >> 4;
    const int wm = w >> 1, wn = w & 1;

    __shared__ bf16 Pl[128 * 136];   // [128 q][128 kk] padded +8

    bf16x8 af[4][2];
    #pragma unroll
    for (int fm = 0; fm < 4; ++fm)
        #pragma unroll
        for (int ks = 0; ks < 2; ++ks)
            af[fm][ks] = *(const bf16x8*)(qb + (size_t)(q0 + wm * 64 + fm * 16 + lr) * 64 + ks * 32 + lg * 8);

    f32x4 pacc[2][4] = {};

    for (int kk0 = 0; kk0 < 1024; kk0 += 128) {
        bf16x8 bfr[4][2];
        #pragma unroll
        for (int fn = 0; fn < 4; ++fn)
            #pragma unroll
            for (int ks = 0; ks < 2; ++ks)
                bfr[fn][ks] = *(const bf16x8*)(kb + (size_t)(kk0 + wn * 64 + fn * 16 + lr) * 64 + ks * 32 + lg * 8);
        float linv[4];
        #pragma unroll
        for (int fn = 0; fn < 4; ++fn)
            linv[fn] = inv_colsum[(size_t)bh * 1024 + kk0 + wn * 64 + fn * 16 + lr];

        #pragma unroll
        for (int fm = 0; fm < 4; ++fm)
            #pragma unroll
            for (int fn = 0; fn < 4; ++fn) {
                f32x4 c = {0.f, 0.f, 0.f, 0.f};
                c = MFMA(af[fm][0], bfr[fn][0], c);
                c = MFMA(af[fm][1], bfr[fn][1], c);
                const int rl0 = wm * 64 + fm * 16 + lg * 4;   // local q row base
                const int cl = wn * 64 + fn * 16 + lr;        // local kk col
                const size_t mbase = (size_t)b * 1048576 + (size_t)(q0 + rl0) * 1024 + (kk0 + cl);
                const size_t abase = ((size_t)bh * 1024 + (q0 + rl0)) * 1024 + (kk0 + cl);
                #pragma unroll
                for (int r = 0; r < 4; ++r) {
                    const float aval = mask[mbase + (size_t)r * 1024] ? 0.f
                                                                      : __expf(c[r]) * linv[fn];
                    attn_out[abase + (size_t)r * 1024] = aval;
                    Pl[(rl0 + r) * 136 + cl] = f2b(aval);
                }
            }
        __syncthreads();
        // PV: each wave owns 32 q-rows x 64 d-cols
        #pragma unroll
        for (int ks2 = 0; ks2 < 4; ++ks2) {
            bf16x8 pa[2];
            #pragma unroll
            for (int fm2 = 0; fm2 < 2; ++fm2)
                pa[fm2] = *(const bf16x8*)&Pl[(w * 32 + fm2 * 16 + lr) * 136 + ks2 * 32 + lg * 8];
            #pragma unroll
            for (int fn2 = 0; fn2 < 4; ++fn2) {
                const bf16x8 vv = *(const bf16x8*)(vb + (size_t)(fn2 * 16 + lr) * 1024 + kk0 + ks2 * 32 + lg * 8);
                pacc[0][fn2] = MFMA(pa[0], vv, pacc[0][fn2]);
                pacc[1][fn2] = MFMA(pa[1], vv, pacc[1][fn2]);
            }
        }
        __syncthreads();
    }

    #pragma unroll
    for (int fm2 = 0; fm2 < 2; ++fm2)
        #pragma unroll
        for (int fn2 = 0; fn2 < 4; ++fn2)
            #pragma unroll
            for (int r = 0; r < 4; ++r) {
                const int qrow = q0 + w * 32 + fm2 * 16 + lg * 4 + r;
                const int d = fn2 * 16 + lr;
                attn_head[((size_t)b * 1024 + qrow) * 1024 + h * 64 + d] = f2b(pacc[fm2][fn2][r]);
            }
}

// ---------------------------------------------------------------------------
// Output projection: attn_head bf16 [4096][1024] @ W_O (+ residual Q) -> proj f32
// ---------------------------------------------------------------------------
__global__ __launch_bounds__(256) void k_outproj(
    const bf16* __restrict__ Ah, const bf16* __restrict__ WTo,
    const float* __restrict__ Qres, float* __restrict__ proj)
{
    __shared__ bf16 As[128 * 72];
    __shared__ bf16 Bs[128 * 72];

    const int tid = threadIdx.x;
    const int lane = tid & 63, w = tid >> 6;
    const int lr = lane & 15, lg = lane >> 4;
    const int wm = w >> 1, wn = w & 1;
    const int m0 = blockIdx.y * 128, n0 = blockIdx.x * 128;

    f32x4 acc[4][4] = {};

    for (int k0 = 0; k0 < 1024; k0 += 64) {
        #pragma unroll
        for (int i = 0; i < 4; ++i) {
            const int lin = i * 2048 + tid * 8;
            const int rr = lin >> 6, cc = lin & 63;
            *(bf16x8*)&As[rr * 72 + cc] = *(const bf16x8*)(Ah + (size_t)(m0 + rr) * 1024 + k0 + cc);
            *(bf16x8*)&Bs[rr * 72 + cc] = *(const bf16x8*)(WTo + (size_t)(n0 + rr) * 1024 + k0 + cc);
        }
        __syncthreads();
        #pragma unroll
        for (int ks = 0; ks < 2; ++ks) {
            bf16x8 a[4], bb[4];
            #pragma unroll
            for (int fm = 0; fm < 4; ++fm)
                a[fm] = *(const bf16x8*)&As[(wm * 64 + fm * 16 + lr) * 72 + ks * 32 + lg * 8];
            #pragma unroll
            for (int fn = 0; fn < 4; ++fn)
                bb[fn] = *(const bf16x8*)&Bs[(wn * 64 + fn * 16 + lr) * 72 + ks * 32 + lg * 8];
            #pragma unroll
            for (int fm = 0; fm < 4; ++fm)
                #pragma unroll
                for (int fn = 0; fn < 4; ++fn)
                    acc[fm][fn] = MFMA(a[fm], bb[fn], acc[fm][fn]);
        }
        __syncthreads();
    }

    #pragma unroll
    for (int fm = 0; fm < 4; ++fm)
        #pragma unroll
        for (int fn = 0; fn < 4; ++fn)
            #pragma unroll
            for (int r = 0; r < 4; ++r) {
                const int m = m0 + wm * 64 + fm * 16 + lg * 4 + r;
                const int n = n0 + wn * 64 + fn * 16 + lr;
                proj[(size_t)m * 1024 + n] = acc[fm][fn][r] + Qres[(size_t)m * 1024 + n];
            }
}

// ---------------------------------------------------------------------------
// Row LayerNorm over D=1024: block per row, 256 threads x float4.
// ---------------------------------------------------------------------------
__global__ __launch_bounds__(256) void k_ln(
    const float* __restrict__ proj, const float* __restrict__ gam,
    const float* __restrict__ bet, float* __restrict__ out)
{
    const int row = blockIdx.x;
    const int t = threadIdx.x;
    const int lane = t & 63, w = t >> 6;
    const float4 x = *(const float4*)(proj + (size_t)row * 1024 + t * 4);
    float s = x.x + x.y + x.z + x.w;
    float ss = x.x * x.x + x.y * x.y + x.z * x.z + x.w * x.w;
    #pragma unroll
    for (int o = 1; o < 64; o <<= 1) {
        s += __shfl_xor(s, o);
        ss += __shfl_xor(ss, o);
    }
    __shared__ float rs[4], rss[4];
    if (lane == 0) { rs[w] = s; rss[w] = ss; }
    __syncthreads();
    const float S1 = rs[0] + rs[1] + rs[2] + rs[3];
    const float S2 = rss[0] + rss[1] + rss[2] + rss[3];
    const float mu = S1 * (1.0f / 1024.0f);
    const float rstd = rsqrtf(S2 * (1.0f / 1024.0f) - mu * mu + 1e-5f);
    const float4 gg = *(const float4*)(gam + t * 4);
    const float4 bb = *(const float4*)(bet + t * 4);
    float4 y;
    y.x = (x.x - mu) * rstd * gg.x + bb.x;
    y.y = (x.y - mu) * rstd * gg.y + bb.y;
    y.z = (x.z - mu) * rstd * gg.z + bb.z;
    y.w = (x.w - mu) * rstd * gg.w + bb.w;
    *(float4*)(out + (size_t)row * 1024 + t * 4) = y;
}

// ---------------------------------------------------------------------------
extern "C" void kernel_launch(void* const* d_in, const int* in_sizes, int n_in,
                              void* d_out, int out_size, void* d_ws, size_t ws_size,
                              hipStream_t stream)
{
    const float* Q  = (const float*)d_in[0];
    const float* K  = (const float*)d_in[1];
    const float* V  = (const float*)d_in[2];
    const unsigned char* mask = (const unsigned char*)d_in[3];
    const float* W_Q = (const float*)d_in[4];
    const float* W_K = (const float*)d_in[5];
    const float* W_V = (const float*)d_in[6];
    const float* W_O = (const float*)d_in[7];
    const float* gam = (const float*)d_in[8];
    const float* bet = (const float*)d_in[9];

    float* out  = (float*)d_out;                     // [B,S,D]
    float* attn = out + (size_t)4 * 1024 * 1024;     // [B,H,S,S]

    // workspace layout (bf16 region then f32 region), ~56.3 MB total
    bf16* wsb = (bf16*)d_ws;
    const size_t M1 = 1024 * 1024;
    bf16* WTq = wsb + 0 * M1;
    bf16* WTk = wsb + 1 * M1;
    bf16* WTv = wsb + 2 * M1;
    bf16* WTo = wsb + 3 * M1;
    bf16* qh  = wsb + 4 * M1;    // [B,H,S,64]  4 Mi elems
    bf16* kh  = wsb + 8 * M1;
    bf16* vTh = wsb + 12 * M1;   // [B,H,64,S]
    bf16* Ah  = wsb + 16 * M1;   // attn_head [B,S,H*64]
    float* inv_colsum = (float*)(wsb + 20 * M1);       // 64K f32
    float* proj       = inv_colsum + 65536;            // 4 Mi f32

    const dim3 blk(256);
    k_transpose<<<dim3(32, 32, 4), blk, 0, stream>>>(W_Q, W_K, W_V, W_O, WTq, WTk, WTv, WTo);
    k_proj<<<dim3(8, 32, 3), blk, 0, stream>>>(Q, K, V, WTq, WTk, WTv, qh, kh, vTh);
    k_colsum<<<dim3(8, 64), blk, 0, stream>>>(qh, kh, mask, inv_colsum);
    k_attn<<<dim3(8, 64), blk, 0, stream>>>(qh, kh, vTh, mask, inv_colsum, attn, Ah);
    k_outproj<<<dim3(8, 32), blk, 0, stream>>>(Ah, WTo, Q, proj);
    k_ln<<<dim3(4096), blk, 0, stream>>>(proj, gam, bet, out);
}

// Round 2
// 352.099 us; speedup vs baseline: 1.1055x; 1.1055x over previous
//
#include <hip/hip_runtime.h>
#include <hip/hip_bf16.h>

// Problem constants: B=4, S=1024, D=1024, H=16, DK=DV=64
// Output 0: out [B,S,D] f32 (4 Mi elems). Output 1: attn [B,H,S,S] f32 (64 Mi elems).
// NOTE: softmax is over the QUERY axis (axis=2): attn[b,h,q,k] = exp(s[q,k]) / sum_q' exp(s[q',k]).
//
// R1: scores computed SWAPPED: mfma(A=K_frag, B=Q_frag) -> D[row=key][col=q],
// so each lane holds 4 consecutive key positions -> float4 attn stores (NT),
// uchar4 mask loads, bf16x4 LDS repack. q-tile 64 -> 1024 blocks (4/CU).

typedef __bf16 bf16;
typedef bf16 bf16x4 __attribute__((ext_vector_type(4)));
typedef bf16 bf16x8 __attribute__((ext_vector_type(8)));
typedef float f32x4 __attribute__((ext_vector_type(4)));

#define MFMA(a, b, c) __builtin_amdgcn_mfma_f32_16x16x32_bf16((a), (b), (c), 0, 0, 0)

__device__ __forceinline__ bf16 f2b(float x) { return (bf16)x; }

// ---------------------------------------------------------------------------
// Weight transpose: W f32 [K=1024][N=1024] -> WT bf16 [N][K]
// ---------------------------------------------------------------------------
__global__ __launch_bounds__(256) void k_transpose(
    const float* __restrict__ W0, const float* __restrict__ W1,
    const float* __restrict__ W2, const float* __restrict__ W3,
    bf16* __restrict__ T0, bf16* __restrict__ T1,
    bf16* __restrict__ T2, bf16* __restrict__ T3)
{
    const float* W = blockIdx.z == 0 ? W0 : blockIdx.z == 1 ? W1 : blockIdx.z == 2 ? W2 : W3;
    bf16*        T = blockIdx.z == 0 ? T0 : blockIdx.z == 1 ? T1 : blockIdx.z == 2 ? T2 : T3;
    __shared__ float tile[32][33];
    const int t = threadIdx.x;
    const int r = t >> 3, c = (t & 7) * 4;
    {
        const float4 v = *(const float4*)(W + (size_t)(blockIdx.y * 32 + r) * 1024 + blockIdx.x * 32 + c);
        tile[r][c + 0] = v.x; tile[r][c + 1] = v.y; tile[r][c + 2] = v.z; tile[r][c + 3] = v.w;
    }
    __syncthreads();
    bf16x4 o = { f2b(tile[c + 0][r]), f2b(tile[c + 1][r]), f2b(tile[c + 2][r]), f2b(tile[c + 3][r]) };
    *(bf16x4*)(T + (size_t)(blockIdx.x * 32 + r) * 1024 + blockIdx.y * 32 + c) = o;
}

// ---------------------------------------------------------------------------
// Projection GEMM: X f32 [4096][1024] @ WT^T -> per-head bf16 tensors.
// z=0: q (scaled by 1/8) -> qh [B,H,S,64]; z=1: k -> kh; z=2: v -> vTh [B,H,64,S].
// ---------------------------------------------------------------------------
__global__ __launch_bounds__(256) void k_proj(
    const float* __restrict__ Xq, const float* __restrict__ Xk, const float* __restrict__ Xv,
    const bf16* __restrict__ WTq, const bf16* __restrict__ WTk, const bf16* __restrict__ WTv,
    bf16* __restrict__ qh, bf16* __restrict__ kh, bf16* __restrict__ vTh)
{
    const int z = blockIdx.z;
    const float* X = z == 0 ? Xq : z == 1 ? Xk : Xv;
    const bf16* WT = z == 0 ? WTq : z == 1 ? WTk : WTv;

    __shared__ bf16 As[128 * 72];
    __shared__ bf16 Bs[128 * 72];

    const int tid = threadIdx.x;
    const int lane = tid & 63, w = tid >> 6;
    const int lr = lane & 15, lg = lane >> 4;
    const int wm = w >> 1, wn = w & 1;
    const int m0 = blockIdx.y * 128, n0 = blockIdx.x * 128;

    f32x4 acc[4][4] = {};

    for (int k0 = 0; k0 < 1024; k0 += 64) {
        #pragma unroll
        for (int i = 0; i < 4; ++i) {
            const int lin = i * 2048 + tid * 8;
            const int rr = lin >> 6, cc = lin & 63;
            const float4 v0 = *(const float4*)(X + (size_t)(m0 + rr) * 1024 + k0 + cc);
            const float4 v1 = *(const float4*)(X + (size_t)(m0 + rr) * 1024 + k0 + cc + 4);
            bf16x8 o = { f2b(v0.x), f2b(v0.y), f2b(v0.z), f2b(v0.w),
                         f2b(v1.x), f2b(v1.y), f2b(v1.z), f2b(v1.w) };
            *(bf16x8*)&As[rr * 72 + cc] = o;
            *(bf16x8*)&Bs[rr * 72 + cc] = *(const bf16x8*)(WT + (size_t)(n0 + rr) * 1024 + k0 + cc);
        }
        __syncthreads();
        #pragma unroll
        for (int ks = 0; ks < 2; ++ks) {
            bf16x8 a[4], bb[4];
            #pragma unroll
            for (int fm = 0; fm < 4; ++fm)
                a[fm] = *(const bf16x8*)&As[(wm * 64 + fm * 16 + lr) * 72 + ks * 32 + lg * 8];
            #pragma unroll
            for (int fn = 0; fn < 4; ++fn)
                bb[fn] = *(const bf16x8*)&Bs[(wn * 64 + fn * 16 + lr) * 72 + ks * 32 + lg * 8];
            #pragma unroll
            for (int fm = 0; fm < 4; ++fm)
                #pragma unroll
                for (int fn = 0; fn < 4; ++fn)
                    acc[fm][fn] = MFMA(a[fm], bb[fn], acc[fm][fn]);
        }
        __syncthreads();
    }

    if (z < 2) {
        const float scale = (z == 0) ? 0.125f : 1.0f;
        bf16* dst = (z == 0) ? qh : kh;
        #pragma unroll
        for (int fm = 0; fm < 4; ++fm)
            #pragma unroll
            for (int fn = 0; fn < 4; ++fn)
                #pragma unroll
                for (int r = 0; r < 4; ++r) {
                    const int m = m0 + wm * 64 + fm * 16 + lg * 4 + r;
                    const int n = n0 + wn * 64 + fn * 16 + lr;
                    const int b = m >> 10, s = m & 1023, h = n >> 6, d = n & 63;
                    dst[(((size_t)(b * 16 + h)) * 1024 + s) * 64 + d] = f2b(acc[fm][fn][r] * scale);
                }
    } else {
        #pragma unroll
        for (int fm = 0; fm < 4; ++fm)
            #pragma unroll
            for (int fn = 0; fn < 4; ++fn) {
                const int m = m0 + wm * 64 + fm * 16 + lg * 4;
                const int n = n0 + wn * 64 + fn * 16 + lr;
                const int b = m >> 10, s = m & 1023, h = n >> 6, d = n & 63;
                bf16x4 o = { f2b(acc[fm][fn][0]), f2b(acc[fm][fn][1]),
                             f2b(acc[fm][fn][2]), f2b(acc[fm][fn][3]) };
                *(bf16x4*)&vTh[(((size_t)(b * 16 + h)) * 64 + d) * 1024 + s] = o;
            }
    }
}

// ---------------------------------------------------------------------------
// Column softmax denominators: inv_colsum[bh][k] = 1 / sum_q exp(s[q][k]).
// Swapped MFMA: lane holds 4 consecutive keys at one q -> uchar4 mask loads.
// Block: 64 key-cols, full q sweep; waves split q. Grid (16, 64).
// ---------------------------------------------------------------------------
__global__ __launch_bounds__(256) void k_colsum(
    const bf16* __restrict__ qh, const bf16* __restrict__ kh,
    const unsigned char* __restrict__ mask, float* __restrict__ inv_colsum)
{
    const int bh = blockIdx.y;
    const int b = bh >> 4;
    const int kk0 = blockIdx.x * 64;
    const bf16* qb = qh + (size_t)bh * 65536;
    const bf16* kb = kh + (size_t)bh * 65536;

    const int tid = threadIdx.x;
    const int lane = tid & 63, w = tid >> 6;
    const int lr = lane & 15, lg = lane >> 4;

    bf16x8 bfr[4][2];
    #pragma unroll
    for (int fn = 0; fn < 4; ++fn)
        #pragma unroll
        for (int ks = 0; ks < 2; ++ks)
            bfr[fn][ks] = *(const bf16x8*)(kb + (size_t)(kk0 + fn * 16 + lr) * 64 + ks * 32 + lg * 8);

    float colacc[4][4] = {};

    for (int q0 = 0; q0 < 1024; q0 += 128) {
        #pragma unroll
        for (int fm = 0; fm < 2; ++fm) {
            const int q = q0 + w * 32 + fm * 16 + lr;
            const bf16x8 a0 = *(const bf16x8*)(qb + (size_t)q * 64 + lg * 8);
            const bf16x8 a1 = *(const bf16x8*)(qb + (size_t)q * 64 + 32 + lg * 8);
            #pragma unroll
            for (int fn = 0; fn < 4; ++fn) {
                f32x4 c = {0.f, 0.f, 0.f, 0.f};
                c = MFMA(bfr[fn][0], a0, c);
                c = MFMA(bfr[fn][1], a1, c);
                const unsigned int m4 = *(const unsigned int*)(
                    mask + (size_t)b * 1048576 + (size_t)q * 1024 + kk0 + fn * 16 + lg * 4);
                #pragma unroll
                for (int r = 0; r < 4; ++r)
                    colacc[fn][r] += ((m4 >> (8 * r)) & 255u) ? 0.f : __expf(c[r]);
            }
        }
    }

    __shared__ float csum[4][64];
    #pragma unroll
    for (int fn = 0; fn < 4; ++fn)
        #pragma unroll
        for (int r = 0; r < 4; ++r) {
            float v = colacc[fn][r];
            v += __shfl_xor(v, 1);
            v += __shfl_xor(v, 2);
            v += __shfl_xor(v, 4);
            v += __shfl_xor(v, 8);
            if (lr == 0) csum[w][fn * 16 + lg * 4 + r] = v;
        }
    __syncthreads();
    if (tid < 64) {
        const float s = csum[0][tid] + csum[1][tid] + csum[2][tid] + csum[3][tid];
        inv_colsum[(size_t)bh * 1024 + kk0 + tid] = 1.0f / s;
    }
}

// ---------------------------------------------------------------------------
// Fused: recompute scores (swapped), attn = exp(s)*inv (NT float4 store),
// repack P to LDS (bf16x4), PV via MFMA -> attn_head [B,S,H*64] bf16.
// Block: 64 q-rows. Grid (16, 64).
// ---------------------------------------------------------------------------
__global__ __launch_bounds__(256) void k_attn(
    const bf16* __restrict__ qh, const bf16* __restrict__ kh, const bf16* __restrict__ vTh,
    const unsigned char* __restrict__ mask, const float* __restrict__ inv_colsum,
    float* __restrict__ attn_out, bf16* __restrict__ attn_head)
{
    const int bh = blockIdx.y;
    const int b = bh >> 4, h = bh & 15;
    const int q0 = blockIdx.x * 64;
    const bf16* qb = qh + (size_t)bh * 65536;
    const bf16* kb = kh + (size_t)bh * 65536;
    const bf16* vb = vTh + (size_t)bh * 65536;

    const int tid = threadIdx.x;
    const int lane = tid & 63, w = tid >> 6;
    const int lr = lane & 15, lg = lane >> 4;
    const int wm = w >> 1, wn = w & 1;

    __shared__ bf16 Pl[64 * 136];   // [64 q][128 k] +8 pad

    bf16x8 af[2][2];
    #pragma unroll
    for (int fm = 0; fm < 2; ++fm)
        #pragma unroll
        for (int ks = 0; ks < 2; ++ks)
            af[fm][ks] = *(const bf16x8*)(qb + (size_t)(q0 + wm * 32 + fm * 16 + lr) * 64 + ks * 32 + lg * 8);

    f32x4 pacc[4] = {};

    for (int kk0 = 0; kk0 < 1024; kk0 += 128) {
        bf16x8 bfr[4][2];
        #pragma unroll
        for (int fn = 0; fn < 4; ++fn)
            #pragma unroll
            for (int ks = 0; ks < 2; ++ks)
                bfr[fn][ks] = *(const bf16x8*)(kb + (size_t)(kk0 + wn * 64 + fn * 16 + lr) * 64 + ks * 32 + lg * 8);
        f32x4 linv[4];
        #pragma unroll
        for (int fn = 0; fn < 4; ++fn)
            linv[fn] = *(const f32x4*)(inv_colsum + (size_t)bh * 1024 + kk0 + wn * 64 + fn * 16 + lg * 4);

        #pragma unroll
        for (int fm = 0; fm < 2; ++fm)
            #pragma unroll
            for (int fn = 0; fn < 4; ++fn) {
                f32x4 c = {0.f, 0.f, 0.f, 0.f};
                c = MFMA(bfr[fn][0], af[fm][0], c);   // SWAPPED: D[key][q]
                c = MFMA(bfr[fn][1], af[fm][1], c);
                const int q = q0 + wm * 32 + fm * 16 + lr;
                const int kcol = kk0 + wn * 64 + fn * 16 + lg * 4;
                const unsigned int m4 = *(const unsigned int*)(
                    mask + (size_t)b * 1048576 + (size_t)q * 1024 + kcol);
                f32x4 aval;
                #pragma unroll
                for (int r = 0; r < 4; ++r)
                    aval[r] = ((m4 >> (8 * r)) & 255u) ? 0.f : __expf(c[r]) * linv[fn][r];
                __builtin_nontemporal_store(
                    aval, (f32x4*)(attn_out + ((size_t)bh * 1024 + q) * 1024 + kcol));
                bf16x4 pb = { f2b(aval[0]), f2b(aval[1]), f2b(aval[2]), f2b(aval[3]) };
                *(bf16x4*)&Pl[(wm * 32 + fm * 16 + lr) * 136 + wn * 64 + fn * 16 + lg * 4] = pb;
            }
        __syncthreads();
        // PV: wave w owns q rows w*16..w*16+15, all 64 d
        #pragma unroll
        for (int ks2 = 0; ks2 < 4; ++ks2) {
            const bf16x8 pa = *(const bf16x8*)&Pl[(w * 16 + lr) * 136 + ks2 * 32 + lg * 8];
            #pragma unroll
            for (int fn2 = 0; fn2 < 4; ++fn2) {
                const bf16x8 vv = *(const bf16x8*)(vb + (size_t)(fn2 * 16 + lr) * 1024 + kk0 + ks2 * 32 + lg * 8);
                pacc[fn2] = MFMA(pa, vv, pacc[fn2]);
            }
        }
        __syncthreads();
    }

    #pragma unroll
    for (int fn2 = 0; fn2 < 4; ++fn2)
        #pragma unroll
        for (int r = 0; r < 4; ++r) {
            const int qrow = q0 + w * 16 + lg * 4 + r;
            const int d = fn2 * 16 + lr;
            attn_head[((size_t)b * 1024 + qrow) * 1024 + h * 64 + d] = f2b(pacc[fn2][r]);
        }
}

// ---------------------------------------------------------------------------
// Output projection: attn_head bf16 [4096][1024] @ W_O (+ residual Q) -> proj f32
// ---------------------------------------------------------------------------
__global__ __launch_bounds__(256) void k_outproj(
    const bf16* __restrict__ Ah, const bf16* __restrict__ WTo,
    const float* __restrict__ Qres, float* __restrict__ proj)
{
    __shared__ bf16 As[128 * 72];
    __shared__ bf16 Bs[128 * 72];

    const int tid = threadIdx.x;
    const int lane = tid & 63, w = tid >> 6;
    const int lr = lane & 15, lg = lane >> 4;
    const int wm = w >> 1, wn = w & 1;
    const int m0 = blockIdx.y * 128, n0 = blockIdx.x * 128;

    f32x4 acc[4][4] = {};

    for (int k0 = 0; k0 < 1024; k0 += 64) {
        #pragma unroll
        for (int i = 0; i < 4; ++i) {
            const int lin = i * 2048 + tid * 8;
            const int rr = lin >> 6, cc = lin & 63;
            *(bf16x8*)&As[rr * 72 + cc] = *(const bf16x8*)(Ah + (size_t)(m0 + rr) * 1024 + k0 + cc);
            *(bf16x8*)&Bs[rr * 72 + cc] = *(const bf16x8*)(WTo + (size_t)(n0 + rr) * 1024 + k0 + cc);
        }
        __syncthreads();
        #pragma unroll
        for (int ks = 0; ks < 2; ++ks) {
            bf16x8 a[4], bb[4];
            #pragma unroll
            for (int fm = 0; fm < 4; ++fm)
                a[fm] = *(const bf16x8*)&As[(wm * 64 + fm * 16 + lr) * 72 + ks * 32 + lg * 8];
            #pragma unroll
            for (int fn = 0; fn < 4; ++fn)
                bb[fn] = *(const bf16x8*)&Bs[(wn * 64 + fn * 16 + lr) * 72 + ks * 32 + lg * 8];
            #pragma unroll
            for (int fm = 0; fm < 4; ++fm)
                #pragma unroll
                for (int fn = 0; fn < 4; ++fn)
                    acc[fm][fn] = MFMA(a[fm], bb[fn], acc[fm][fn]);
        }
        __syncthreads();
    }

    #pragma unroll
    for (int fm = 0; fm < 4; ++fm)
        #pragma unroll
        for (int fn = 0; fn < 4; ++fn)
            #pragma unroll
            for (int r = 0; r < 4; ++r) {
                const int m = m0 + wm * 64 + fm * 16 + lg * 4 + r;
                const int n = n0 + wn * 64 + fn * 16 + lr;
                proj[(size_t)m * 1024 + n] = acc[fm][fn][r] + Qres[(size_t)m * 1024 + n];
            }
}

// ---------------------------------------------------------------------------
// Row LayerNorm over D=1024.
// ---------------------------------------------------------------------------
__global__ __launch_bounds__(256) void k_ln(
    const float* __restrict__ proj, const float* __restrict__ gam,
    const float* __restrict__ bet, float* __restrict__ out)
{
    const int row = blockIdx.x;
    const int t = threadIdx.x;
    const int lane = t & 63, w = t >> 6;
    const float4 x = *(const float4*)(proj + (size_t)row * 1024 + t * 4);
    float s = x.x + x.y + x.z + x.w;
    float ss = x.x * x.x + x.y * x.y + x.z * x.z + x.w * x.w;
    #pragma unroll
    for (int o = 1; o < 64; o <<= 1) {
        s += __shfl_xor(s, o);
        ss += __shfl_xor(ss, o);
    }
    __shared__ float rs[4], rss[4];
    if (lane == 0) { rs[w] = s; rss[w] = ss; }
    __syncthreads();
    const float S1 = rs[0] + rs[1] + rs[2] + rs[3];
    const float S2 = rss[0] + rss[1] + rss[2] + rss[3];
    const float mu = S1 * (1.0f / 1024.0f);
    const float rstd = rsqrtf(S2 * (1.0f / 1024.0f) - mu * mu + 1e-5f);
    const float4 gg = *(const float4*)(gam + t * 4);
    const float4 bb = *(const float4*)(bet + t * 4);
    float4 y;
    y.x = (x.x - mu) * rstd * gg.x + bb.x;
    y.y = (x.y - mu) * rstd * gg.y + bb.y;
    y.z = (x.z - mu) * rstd * gg.z + bb.z;
    y.w = (x.w - mu) * rstd * gg.w + bb.w;
    *(float4*)(out + (size_t)row * 1024 + t * 4) = y;
}

// ---------------------------------------------------------------------------
extern "C" void kernel_launch(void* const* d_in, const int* in_sizes, int n_in,
                              void* d_out, int out_size, void* d_ws, size_t ws_size,
                              hipStream_t stream)
{
    const float* Q  = (const float*)d_in[0];
    const float* K  = (const float*)d_in[1];
    const float* V  = (const float*)d_in[2];
    const unsigned char* mask = (const unsigned char*)d_in[3];
    const float* W_Q = (const float*)d_in[4];
    const float* W_K = (const float*)d_in[5];
    const float* W_V = (const float*)d_in[6];
    const float* W_O = (const float*)d_in[7];
    const float* gam = (const float*)d_in[8];
    const float* bet = (const float*)d_in[9];

    float* out  = (float*)d_out;                     // [B,S,D]
    float* attn = out + (size_t)4 * 1024 * 1024;     // [B,H,S,S]

    bf16* wsb = (bf16*)d_ws;
    const size_t M1 = 1024 * 1024;
    bf16* WTq = wsb + 0 * M1;
    bf16* WTk = wsb + 1 * M1;
    bf16* WTv = wsb + 2 * M1;
    bf16* WTo = wsb + 3 * M1;
    bf16* qh  = wsb + 4 * M1;    // [B,H,S,64]
    bf16* kh  = wsb + 8 * M1;
    bf16* vTh = wsb + 12 * M1;   // [B,H,64,S]
    bf16* Ah  = wsb + 16 * M1;   // attn_head [B,S,H*64]
    float* inv_colsum = (float*)(wsb + 20 * M1);
    float* proj       = inv_colsum + 65536;

    const dim3 blk(256);
    k_transpose<<<dim3(32, 32, 4), blk, 0, stream>>>(W_Q, W_K, W_V, W_O, WTq, WTk, WTv, WTo);
    k_proj<<<dim3(8, 32, 3), blk, 0, stream>>>(Q, K, V, WTq, WTk, WTv, qh, kh, vTh);
    k_colsum<<<dim3(16, 64), blk, 0, stream>>>(qh, kh, mask, inv_colsum);
    k_attn<<<dim3(16, 64), blk, 0, stream>>>(qh, kh, vTh, mask, inv_colsum, attn, Ah);
    k_outproj<<<dim3(8, 32), blk, 0, stream>>>(Ah, WTo, Q, proj);
    k_ln<<<dim3(4096), blk, 0, stream>>>(proj, gam, bet, out);
}

// Round 3
// 348.040 us; speedup vs baseline: 1.1184x; 1.0117x over previous
//
#include <hip/hip_runtime.h>
#include <hip/hip_bf16.h>

// Problem constants: B=4, S=1024, D=1024, H=16, DK=DV=64
// Output 0: out [B,S,D] f32. Output 1: attn [B,H,S,S] f32 (268 MB!).
// Softmax over QUERY axis: attn[b,h,q,k] = exp(s[q,k]) / sum_q' exp(s[q',k]).
//
// R2: attn stores via LDS-staged coalesced pass (NT direct stores caused
// write amplification 271->358 MB and ~1.7 TB/s write path in R1).

typedef __bf16 bf16;
typedef bf16 bf16x4 __attribute__((ext_vector_type(4)));
typedef bf16 bf16x8 __attribute__((ext_vector_type(8)));
typedef float f32x4 __attribute__((ext_vector_type(4)));

#define MFMA(a, b, c) __builtin_amdgcn_mfma_f32_16x16x32_bf16((a), (b), (c), 0, 0, 0)

__device__ __forceinline__ bf16 f2b(float x) { return (bf16)x; }

// ---------------------------------------------------------------------------
// Weight transpose: W f32 [K=1024][N=1024] -> WT bf16 [N][K]
// ---------------------------------------------------------------------------
__global__ __launch_bounds__(256) void k_transpose(
    const float* __restrict__ W0, const float* __restrict__ W1,
    const float* __restrict__ W2, const float* __restrict__ W3,
    bf16* __restrict__ T0, bf16* __restrict__ T1,
    bf16* __restrict__ T2, bf16* __restrict__ T3)
{
    const float* W = blockIdx.z == 0 ? W0 : blockIdx.z == 1 ? W1 : blockIdx.z == 2 ? W2 : W3;
    bf16*        T = blockIdx.z == 0 ? T0 : blockIdx.z == 1 ? T1 : blockIdx.z == 2 ? T2 : T3;
    __shared__ float tile[32][33];
    const int t = threadIdx.x;
    const int r = t >> 3, c = (t & 7) * 4;
    {
        const float4 v = *(const float4*)(W + (size_t)(blockIdx.y * 32 + r) * 1024 + blockIdx.x * 32 + c);
        tile[r][c + 0] = v.x; tile[r][c + 1] = v.y; tile[r][c + 2] = v.z; tile[r][c + 3] = v.w;
    }
    __syncthreads();
    bf16x4 o = { f2b(tile[c + 0][r]), f2b(tile[c + 1][r]), f2b(tile[c + 2][r]), f2b(tile[c + 3][r]) };
    *(bf16x4*)(T + (size_t)(blockIdx.x * 32 + r) * 1024 + blockIdx.y * 32 + c) = o;
}

// ---------------------------------------------------------------------------
// Projection GEMM: X f32 [4096][1024] @ WT^T -> per-head bf16 tensors.
// ---------------------------------------------------------------------------
__global__ __launch_bounds__(256) void k_proj(
    const float* __restrict__ Xq, const float* __restrict__ Xk, const float* __restrict__ Xv,
    const bf16* __restrict__ WTq, const bf16* __restrict__ WTk, const bf16* __restrict__ WTv,
    bf16* __restrict__ qh, bf16* __restrict__ kh, bf16* __restrict__ vTh)
{
    const int z = blockIdx.z;
    const float* X = z == 0 ? Xq : z == 1 ? Xk : Xv;
    const bf16* WT = z == 0 ? WTq : z == 1 ? WTk : WTv;

    __shared__ bf16 As[128 * 72];
    __shared__ bf16 Bs[128 * 72];

    const int tid = threadIdx.x;
    const int lane = tid & 63, w = tid >> 6;
    const int lr = lane & 15, lg = lane >> 4;
    const int wm = w >> 1, wn = w & 1;
    const int m0 = blockIdx.y * 128, n0 = blockIdx.x * 128;

    f32x4 acc[4][4] = {};

    for (int k0 = 0; k0 < 1024; k0 += 64) {
        #pragma unroll
        for (int i = 0; i < 4; ++i) {
            const int lin = i * 2048 + tid * 8;
            const int rr = lin >> 6, cc = lin & 63;
            const float4 v0 = *(const float4*)(X + (size_t)(m0 + rr) * 1024 + k0 + cc);
            const float4 v1 = *(const float4*)(X + (size_t)(m0 + rr) * 1024 + k0 + cc + 4);
            bf16x8 o = { f2b(v0.x), f2b(v0.y), f2b(v0.z), f2b(v0.w),
                         f2b(v1.x), f2b(v1.y), f2b(v1.z), f2b(v1.w) };
            *(bf16x8*)&As[rr * 72 + cc] = o;
            *(bf16x8*)&Bs[rr * 72 + cc] = *(const bf16x8*)(WT + (size_t)(n0 + rr) * 1024 + k0 + cc);
        }
        __syncthreads();
        #pragma unroll
        for (int ks = 0; ks < 2; ++ks) {
            bf16x8 a[4], bb[4];
            #pragma unroll
            for (int fm = 0; fm < 4; ++fm)
                a[fm] = *(const bf16x8*)&As[(wm * 64 + fm * 16 + lr) * 72 + ks * 32 + lg * 8];
            #pragma unroll
            for (int fn = 0; fn < 4; ++fn)
                bb[fn] = *(const bf16x8*)&Bs[(wn * 64 + fn * 16 + lr) * 72 + ks * 32 + lg * 8];
            #pragma unroll
            for (int fm = 0; fm < 4; ++fm)
                #pragma unroll
                for (int fn = 0; fn < 4; ++fn)
                    acc[fm][fn] = MFMA(a[fm], bb[fn], acc[fm][fn]);
        }
        __syncthreads();
    }

    if (z < 2) {
        const float scale = (z == 0) ? 0.125f : 1.0f;
        bf16* dst = (z == 0) ? qh : kh;
        #pragma unroll
        for (int fm = 0; fm < 4; ++fm)
            #pragma unroll
            for (int fn = 0; fn < 4; ++fn)
                #pragma unroll
                for (int r = 0; r < 4; ++r) {
                    const int m = m0 + wm * 64 + fm * 16 + lg * 4 + r;
                    const int n = n0 + wn * 64 + fn * 16 + lr;
                    const int b = m >> 10, s = m & 1023, h = n >> 6, d = n & 63;
                    dst[(((size_t)(b * 16 + h)) * 1024 + s) * 64 + d] = f2b(acc[fm][fn][r] * scale);
                }
    } else {
        #pragma unroll
        for (int fm = 0; fm < 4; ++fm)
            #pragma unroll
            for (int fn = 0; fn < 4; ++fn) {
                const int m = m0 + wm * 64 + fm * 16 + lg * 4;
                const int n = n0 + wn * 64 + fn * 16 + lr;
                const int b = m >> 10, s = m & 1023, h = n >> 6, d = n & 63;
                bf16x4 o = { f2b(acc[fm][fn][0]), f2b(acc[fm][fn][1]),
                             f2b(acc[fm][fn][2]), f2b(acc[fm][fn][3]) };
                *(bf16x4*)&vTh[(((size_t)(b * 16 + h)) * 64 + d) * 1024 + s] = o;
            }
    }
}

// ---------------------------------------------------------------------------
// Column softmax denominators: inv_colsum[bh][k] = 1 / sum_q exp(s[q][k]).
// Swapped MFMA: lane holds 4 consecutive keys at one q -> uchar4 mask loads.
// ---------------------------------------------------------------------------
__global__ __launch_bounds__(256) void k_colsum(
    const bf16* __restrict__ qh, const bf16* __restrict__ kh,
    const unsigned char* __restrict__ mask, float* __restrict__ inv_colsum)
{
    const int bh = blockIdx.y;
    const int b = bh >> 4;
    const int kk0 = blockIdx.x * 64;
    const bf16* qb = qh + (size_t)bh * 65536;
    const bf16* kb = kh + (size_t)bh * 65536;

    const int tid = threadIdx.x;
    const int lane = tid & 63, w = tid >> 6;
    const int lr = lane & 15, lg = lane >> 4;

    bf16x8 bfr[4][2];
    #pragma unroll
    for (int fn = 0; fn < 4; ++fn)
        #pragma unroll
        for (int ks = 0; ks < 2; ++ks)
            bfr[fn][ks] = *(const bf16x8*)(kb + (size_t)(kk0 + fn * 16 + lr) * 64 + ks * 32 + lg * 8);

    float colacc[4][4] = {};

    for (int q0 = 0; q0 < 1024; q0 += 128) {
        #pragma unroll
        for (int fm = 0; fm < 2; ++fm) {
            const int q = q0 + w * 32 + fm * 16 + lr;
            const bf16x8 a0 = *(const bf16x8*)(qb + (size_t)q * 64 + lg * 8);
            const bf16x8 a1 = *(const bf16x8*)(qb + (size_t)q * 64 + 32 + lg * 8);
            #pragma unroll
            for (int fn = 0; fn < 4; ++fn) {
                f32x4 c = {0.f, 0.f, 0.f, 0.f};
                c = MFMA(bfr[fn][0], a0, c);
                c = MFMA(bfr[fn][1], a1, c);
                const unsigned int m4 = *(const unsigned int*)(
                    mask + (size_t)b * 1048576 + (size_t)q * 1024 + kk0 + fn * 16 + lg * 4);
                #pragma unroll
                for (int r = 0; r < 4; ++r)
                    colacc[fn][r] += ((m4 >> (8 * r)) & 255u) ? 0.f : __expf(c[r]);
            }
        }
    }

    __shared__ float csum[4][64];
    #pragma unroll
    for (int fn = 0; fn < 4; ++fn)
        #pragma unroll
        for (int r = 0; r < 4; ++r) {
            float v = colacc[fn][r];
            v += __shfl_xor(v, 1);
            v += __shfl_xor(v, 2);
            v += __shfl_xor(v, 4);
            v += __shfl_xor(v, 8);
            if (lr == 0) csum[w][fn * 16 + lg * 4 + r] = v;
        }
    __syncthreads();
    if (tid < 64) {
        const float s = csum[0][tid] + csum[1][tid] + csum[2][tid] + csum[3][tid];
        inv_colsum[(size_t)bh * 1024 + kk0 + tid] = 1.0f / s;
    }
}

// ---------------------------------------------------------------------------
// Fused: recompute scores (swapped mfma -> D[key][q]), P = exp(s)*inv -> LDS
// (bf16), then per kk-tile: PV MFMA + fully-coalesced attn store pass from LDS.
// Block: 64 q-rows. Grid (16, 64).
// ---------------------------------------------------------------------------
__global__ __launch_bounds__(256) void k_attn(
    const bf16* __restrict__ qh, const bf16* __restrict__ kh, const bf16* __restrict__ vTh,
    const unsigned char* __restrict__ mask, const float* __restrict__ inv_colsum,
    float* __restrict__ attn_out, bf16* __restrict__ attn_head)
{
    const int bh = blockIdx.y;
    const int b = bh >> 4, h = bh & 15;
    const int q0 = blockIdx.x * 64;
    const bf16* qb = qh + (size_t)bh * 65536;
    const bf16* kb = kh + (size_t)bh * 65536;
    const bf16* vb = vTh + (size_t)bh * 65536;

    const int tid = threadIdx.x;
    const int lane = tid & 63, w = tid >> 6;
    const int lr = lane & 15, lg = lane >> 4;
    const int wm = w >> 1, wn = w & 1;

    __shared__ bf16 Pl[64 * 136];   // [64 q][128 k] +8 pad

    bf16x8 af[2][2];
    #pragma unroll
    for (int fm = 0; fm < 2; ++fm)
        #pragma unroll
        for (int ks = 0; ks < 2; ++ks)
            af[fm][ks] = *(const bf16x8*)(qb + (size_t)(q0 + wm * 32 + fm * 16 + lr) * 64 + ks * 32 + lg * 8);

    f32x4 pacc[4] = {};

    for (int kk0 = 0; kk0 < 1024; kk0 += 128) {
        bf16x8 bfr[4][2];
        #pragma unroll
        for (int fn = 0; fn < 4; ++fn)
            #pragma unroll
            for (int ks = 0; ks < 2; ++ks)
                bfr[fn][ks] = *(const bf16x8*)(kb + (size_t)(kk0 + wn * 64 + fn * 16 + lr) * 64 + ks * 32 + lg * 8);
        f32x4 linv[4];
        #pragma unroll
        for (int fn = 0; fn < 4; ++fn)
            linv[fn] = *(const f32x4*)(inv_colsum + (size_t)bh * 1024 + kk0 + wn * 64 + fn * 16 + lg * 4);

        #pragma unroll
        for (int fm = 0; fm < 2; ++fm)
            #pragma unroll
            for (int fn = 0; fn < 4; ++fn) {
                f32x4 c = {0.f, 0.f, 0.f, 0.f};
                c = MFMA(bfr[fn][0], af[fm][0], c);   // SWAPPED: D[key][q]
                c = MFMA(bfr[fn][1], af[fm][1], c);
                const int q = q0 + wm * 32 + fm * 16 + lr;
                const int kcol = kk0 + wn * 64 + fn * 16 + lg * 4;
                const unsigned int m4 = *(const unsigned int*)(
                    mask + (size_t)b * 1048576 + (size_t)q * 1024 + kcol);
                bf16x4 pb;
                #pragma unroll
                for (int r = 0; r < 4; ++r)
                    pb[r] = f2b(((m4 >> (8 * r)) & 255u) ? 0.f : __expf(c[r]) * linv[fn][r]);
                *(bf16x4*)&Pl[(wm * 32 + fm * 16 + lr) * 136 + wn * 64 + fn * 16 + lg * 4] = pb;
            }
        __syncthreads();

        // PV: wave w owns q rows w*16..w*16+15, all 64 d
        #pragma unroll
        for (int ks2 = 0; ks2 < 4; ++ks2) {
            const bf16x8 pa = *(const bf16x8*)&Pl[(w * 16 + lr) * 136 + ks2 * 32 + lg * 8];
            #pragma unroll
            for (int fn2 = 0; fn2 < 4; ++fn2) {
                const bf16x8 vv = *(const bf16x8*)(vb + (size_t)(fn2 * 16 + lr) * 1024 + kk0 + ks2 * 32 + lg * 8);
                pacc[fn2] = MFMA(pa, vv, pacc[fn2]);
            }
        }

        // Coalesced attn store pass: read Pl bf16, widen to f32 (bits<<16),
        // store 512B-contiguous segments. Wave covers 2 rows x 128 cols per iter.
        {
            const int srow = tid >> 5;          // 0..7
            const int c4 = (tid & 31) * 4;      // f32 col 0..124
            #pragma unroll
            for (int rr = 0; rr < 8; ++rr) {
                const int row = srow + rr * 8;
                const uint2 pv = *(const uint2*)&Pl[row * 136 + c4];
                f32x4 o;
                o[0] = __uint_as_float(pv.x << 16);
                o[1] = __uint_as_float(pv.x & 0xffff0000u);
                o[2] = __uint_as_float(pv.y << 16);
                o[3] = __uint_as_float(pv.y & 0xffff0000u);
                *(f32x4*)(attn_out + ((size_t)bh * 1024 + q0 + row) * 1024 + kk0 + c4) = o;
            }
        }
        __syncthreads();
    }

    #pragma unroll
    for (int fn2 = 0; fn2 < 4; ++fn2)
        #pragma unroll
        for (int r = 0; r < 4; ++r) {
            const int qrow = q0 + w * 16 + lg * 4 + r;
            const int d = fn2 * 16 + lr;
            attn_head[((size_t)b * 1024 + qrow) * 1024 + h * 64 + d] = f2b(pacc[fn2][r]);
        }
}

// ---------------------------------------------------------------------------
// Output projection: attn_head bf16 [4096][1024] @ W_O (+ residual Q) -> proj f32
// ---------------------------------------------------------------------------
__global__ __launch_bounds__(256) void k_outproj(
    const bf16* __restrict__ Ah, const bf16* __restrict__ WTo,
    const float* __restrict__ Qres, float* __restrict__ proj)
{
    __shared__ bf16 As[128 * 72];
    __shared__ bf16 Bs[128 * 72];

    const int tid = threadIdx.x;
    const int lane = tid & 63, w = tid >> 6;
    const int lr = lane & 15, lg = lane >> 4;
    const int wm = w >> 1, wn = w & 1;
    const int m0 = blockIdx.y * 128, n0 = blockIdx.x * 128;

    f32x4 acc[4][4] = {};

    for (int k0 = 0; k0 < 1024; k0 += 64) {
        #pragma unroll
        for (int i = 0; i < 4; ++i) {
            const int lin = i * 2048 + tid * 8;
            const int rr = lin >> 6, cc = lin & 63;
            *(bf16x8*)&As[rr * 72 + cc] = *(const bf16x8*)(Ah + (size_t)(m0 + rr) * 1024 + k0 + cc);
            *(bf16x8*)&Bs[rr * 72 + cc] = *(const bf16x8*)(WTo + (size_t)(n0 + rr) * 1024 + k0 + cc);
        }
        __syncthreads();
        #pragma unroll
        for (int ks = 0; ks < 2; ++ks) {
            bf16x8 a[4], bb[4];
            #pragma unroll
            for (int fm = 0; fm < 4; ++fm)
                a[fm] = *(const bf16x8*)&As[(wm * 64 + fm * 16 + lr) * 72 + ks * 32 + lg * 8];
            #pragma unroll
            for (int fn = 0; fn < 4; ++fn)
                bb[fn] = *(const bf16x8*)&Bs[(wn * 64 + fn * 16 + lr) * 72 + ks * 32 + lg * 8];
            #pragma unroll
            for (int fm = 0; fm < 4; ++fm)
                #pragma unroll
                for (int fn = 0; fn < 4; ++fn)
                    acc[fm][fn] = MFMA(a[fm], bb[fn], acc[fm][fn]);
        }
        __syncthreads();
    }

    #pragma unroll
    for (int fm = 0; fm < 4; ++fm)
        #pragma unroll
        for (int fn = 0; fn < 4; ++fn)
            #pragma unroll
            for (int r = 0; r < 4; ++r) {
                const int m = m0 + wm * 64 + fm * 16 + lg * 4 + r;
                const int n = n0 + wn * 64 + fn * 16 + lr;
                proj[(size_t)m * 1024 + n] = acc[fm][fn][r] + Qres[(size_t)m * 1024 + n];
            }
}

// ---------------------------------------------------------------------------
// Row LayerNorm over D=1024.
// ---------------------------------------------------------------------------
__global__ __launch_bounds__(256) void k_ln(
    const float* __restrict__ proj, const float* __restrict__ gam,
    const float* __restrict__ bet, float* __restrict__ out)
{
    const int row = blockIdx.x;
    const int t = threadIdx.x;
    const int lane = t & 63, w = t >> 6;
    const float4 x = *(const float4*)(proj + (size_t)row * 1024 + t * 4);
    float s = x.x + x.y + x.z + x.w;
    float ss = x.x * x.x + x.y * x.y + x.z * x.z + x.w * x.w;
    #pragma unroll
    for (int o = 1; o < 64; o <<= 1) {
        s += __shfl_xor(s, o);
        ss += __shfl_xor(ss, o);
    }
    __shared__ float rs[4], rss[4];
    if (lane == 0) { rs[w] = s; rss[w] = ss; }
    __syncthreads();
    const float S1 = rs[0] + rs[1] + rs[2] + rs[3];
    const float S2 = rss[0] + rss[1] + rss[2] + rss[3];
    const float mu = S1 * (1.0f / 1024.0f);
    const float rstd = rsqrtf(S2 * (1.0f / 1024.0f) - mu * mu + 1e-5f);
    const float4 gg = *(const float4*)(gam + t * 4);
    const float4 bb = *(const float4*)(bet + t * 4);
    float4 y;
    y.x = (x.x - mu) * rstd * gg.x + bb.x;
    y.y = (x.y - mu) * rstd * gg.y + bb.y;
    y.z = (x.z - mu) * rstd * gg.z + bb.z;
    y.w = (x.w - mu) * rstd * gg.w + bb.w;
    *(float4*)(out + (size_t)row * 1024 + t * 4) = y;
}

// ---------------------------------------------------------------------------
extern "C" void kernel_launch(void* const* d_in, const int* in_sizes, int n_in,
                              void* d_out, int out_size, void* d_ws, size_t ws_size,
                              hipStream_t stream)
{
    const float* Q  = (const float*)d_in[0];
    const float* K  = (const float*)d_in[1];
    const float* V  = (const float*)d_in[2];
    const unsigned char* mask = (const unsigned char*)d_in[3];
    const float* W_Q = (const float*)d_in[4];
    const float* W_K = (const float*)d_in[5];
    const float* W_V = (const float*)d_in[6];
    const float* W_O = (const float*)d_in[7];
    const float* gam = (const float*)d_in[8];
    const float* bet = (const float*)d_in[9];

    float* out  = (float*)d_out;                     // [B,S,D]
    float* attn = out + (size_t)4 * 1024 * 1024;     // [B,H,S,S]

    bf16* wsb = (bf16*)d_ws;
    const size_t M1 = 1024 * 1024;
    bf16* WTq = wsb + 0 * M1;
    bf16* WTk = wsb + 1 * M1;
    bf16* WTv = wsb + 2 * M1;
    bf16* WTo = wsb + 3 * M1;
    bf16* qh  = wsb + 4 * M1;    // [B,H,S,64]
    bf16* kh  = wsb + 8 * M1;
    bf16* vTh = wsb + 12 * M1;   // [B,H,64,S]
    bf16* Ah  = wsb + 16 * M1;   // attn_head [B,S,H*64]
    float* inv_colsum = (float*)(wsb + 20 * M1);
    float* proj       = inv_colsum + 65536;

    const dim3 blk(256);
    k_transpose<<<dim3(32, 32, 4), blk, 0, stream>>>(W_Q, W_K, W_V, W_O, WTq, WTk, WTv, WTo);
    k_proj<<<dim3(8, 32, 3), blk, 0, stream>>>(Q, K, V, WTq, WTk, WTv, qh, kh, vTh);
    k_colsum<<<dim3(16, 64), blk, 0, stream>>>(qh, kh, mask, inv_colsum);
    k_attn<<<dim3(16, 64), blk, 0, stream>>>(qh, kh, vTh, mask, inv_colsum, attn, Ah);
    k_outproj<<<dim3(8, 32), blk, 0, stream>>>(Ah, WTo, Q, proj);
    k_ln<<<dim3(4096), blk, 0, stream>>>(proj, gam, bet, out);
}